// Round 11
// baseline (546.024 us; speedup 1.0000x reference)
//
#include <hip/hip_runtime.h>
#include <hip/hip_fp16.h>
#include <math.h>

#define D 64
#define RB 1024          // nodes per range (must match >>10 / &1023 below)
#define EB 2048          // edges per partition block
#define NRMAX 128        // static LDS sizing; NR = ceil(N/RB) must be <= NRMAX
#define KHOPS 10

// ---- helpers ------------------------------------------------------------

typedef union { uint4 u; __half2 h[4]; } U4H;
typedef float vfloat2 __attribute__((ext_vector_type(2)));

// decode 8 fp8(e4m3, OCP on gfx950) packed in uint2 -> add into f32 acc[8]
__device__ __forceinline__ void acc_fp8x8(uint2 q, float* a) {
    vfloat2 r0 = __builtin_amdgcn_cvt_pk_f32_fp8(q.x, false);
    vfloat2 r1 = __builtin_amdgcn_cvt_pk_f32_fp8(q.x, true);
    vfloat2 r2 = __builtin_amdgcn_cvt_pk_f32_fp8(q.y, false);
    vfloat2 r3 = __builtin_amdgcn_cvt_pk_f32_fp8(q.y, true);
    a[0] += r0.x; a[1] += r0.y; a[2] += r1.x; a[3] += r1.y;
    a[4] += r2.x; a[5] += r2.y; a[6] += r3.x; a[7] += r3.y;
}

// encode 8 f32 -> 8 fp8 in uint2 (HW saturating RNE)
__device__ __forceinline__ uint2 pack_fp8x8(const float* v) {
    uint2 q;
    q.x = __builtin_amdgcn_cvt_pk_fp8_f32(v[0], v[1], 0, false);
    q.x = __builtin_amdgcn_cvt_pk_fp8_f32(v[2], v[3], q.x, true);
    q.y = __builtin_amdgcn_cvt_pk_fp8_f32(v[4], v[5], 0, false);
    q.y = __builtin_amdgcn_cvt_pk_fp8_f32(v[6], v[7], q.y, true);
    return q;
}

// ---- multisplit CSR build (no global atomics anywhere) ------------------

__global__ void countA(const int* __restrict__ dst, int* __restrict__ countsA_T,
                       int E, int NR, int NBLK) {
    __shared__ int hist[NRMAX];
    int t = threadIdx.x;
    for (int i = t; i < NR; i += 256) hist[i] = 0;
    __syncthreads();
    int base = blockIdx.x * EB + t;
    #pragma unroll
    for (int j = 0; j < EB / 256; ++j) {
        int e = base + j * 256;
        if (e < E) atomicAdd(&hist[dst[e] >> 10], 1);
    }
    __syncthreads();
    for (int i = t; i < NR; i += 256) countsA_T[i * NBLK + blockIdx.x] = hist[i];
}

__global__ void block_sums(const int* __restrict__ arr, int* __restrict__ bsum, int n) {
    int base = blockIdx.x * 1024;
    int t = threadIdx.x;
    int v = 0;
    #pragma unroll
    for (int j = 0; j < 4; ++j) {
        int i = base + t + j * 256;
        if (i < n) v += arr[i];
    }
    #pragma unroll
    for (int m = 32; m >= 1; m >>= 1) v += __shfl_xor(v, m, 64);
    __shared__ int ws[4];
    if ((t & 63) == 0) ws[t >> 6] = v;
    __syncthreads();
    if (t == 0) bsum[blockIdx.x] = ws[0] + ws[1] + ws[2] + ws[3];
}

__global__ void scan_bsums(int* __restrict__ bsum, int nb) {
    __shared__ int tmp[1024];
    int t = threadIdx.x;
    int v = (t < nb) ? bsum[t] : 0;
    tmp[t] = v;
    __syncthreads();
    for (int off = 1; off < 1024; off <<= 1) {
        int x = (t >= off) ? tmp[t - off] : 0;
        __syncthreads();
        tmp[t] += x;
        __syncthreads();
    }
    if (t < nb) bsum[t] = tmp[t] - v;
}

__global__ void gen_scan2(const int* __restrict__ arr, const int* __restrict__ bsum,
                          int* __restrict__ out, int n) {
    __shared__ int tmp[1024];
    int base = blockIdx.x * 1024;
    int t = threadIdx.x;
    int i = base + t;
    int v = (i < n) ? arr[i] : 0;
    tmp[t] = v;
    __syncthreads();
    for (int off = 1; off < 1024; off <<= 1) {
        int x = (t >= off) ? tmp[t - off] : 0;
        __syncthreads();
        tmp[t] += x;
        __syncthreads();
    }
    if (i < n) out[i] = bsum[blockIdx.x] + tmp[t] - v;
}

__global__ void passA2(const int* __restrict__ src, const int* __restrict__ dst,
                       const int* __restrict__ baseA, unsigned int* __restrict__ ebuf2,
                       int E, int NR, int NBLK) {
    __shared__ int cur[NRMAX];
    int t = threadIdx.x;
    for (int i = t; i < NR; i += 256) cur[i] = baseA[i * NBLK + blockIdx.x];
    __syncthreads();
    int base = blockIdx.x * EB + t;
    #pragma unroll
    for (int j = 0; j < EB / 256; ++j) {
        int e = base + j * 256;
        if (e < E) {
            int v = dst[e];
            int pos = atomicAdd(&cur[v >> 10], 1);
            ebuf2[pos] = (unsigned int)src[e] | ((unsigned int)(v & (RB - 1)) << 17);
        }
    }
}

__global__ void range_build(const unsigned int* __restrict__ ebuf2,
                            const int* __restrict__ baseA,
                            int* __restrict__ offsets, float* __restrict__ norm,
                            int* __restrict__ csr, int N, int E, int NR, int NBLK) {
    __shared__ int cnt[RB];
    __shared__ int sc[RB];
    int rg = blockIdx.x;
    int t = threadIdx.x;
    int r0 = baseA[rg * NBLK];
    int r1 = (rg + 1 < NR) ? baseA[(rg + 1) * NBLK] : E;
    cnt[t] = 0;
    __syncthreads();
    for (int i = r0 + t; i < r1; i += RB)
        atomicAdd(&cnt[ebuf2[i] >> 17], 1);
    __syncthreads();
    int v = cnt[t];
    sc[t] = v;
    __syncthreads();
    for (int off = 1; off < RB; off <<= 1) {
        int x = (t >= off) ? sc[t - off] : 0;
        __syncthreads();
        sc[t] += x;
        __syncthreads();
    }
    int excl = sc[t] - v;
    int node = rg * RB + t;
    if (node < N) {
        offsets[node] = r0 + excl;
        norm[node] = rsqrtf((float)(v > 1 ? v : 1));
    }
    if (rg == NR - 1 && t == 0) offsets[N] = E;
    __syncthreads();
    cnt[t] = r0 + excl;
    __syncthreads();
    for (int i = r0 + t; i < r1; i += RB) {
        unsigned int u = ebuf2[i];
        int pos = atomicAdd(&cnt[u >> 17], 1);
        csr[pos] = (int)(u & 0x1FFFFu);
    }
}

// ---- hop 0: g0_f16 = f16(f*norm); g0_fp8 = fp8(f*norm); optional pool ---

__global__ void hop0(const float4* __restrict__ feat, const float* __restrict__ s,
                     const float* __restrict__ norm, uint4* __restrict__ g0,
                     uint2* __restrict__ p0, float4* __restrict__ out,
                     int n, int do_pool, int write8) {
    int t = blockIdx.x * blockDim.x + threadIdx.x;
    int node = t >> 3;
    int l = t & 7;
    if (node >= n) return;
    float4 f0 = feat[node * 16 + 2 * l];
    float4 f1 = feat[node * 16 + 2 * l + 1];
    float nv = norm[node];
    float v[8] = {f0.x * nv, f0.y * nv, f0.z * nv, f0.w * nv,
                  f1.x * nv, f1.y * nv, f1.z * nv, f1.w * nv};
    U4H P;
    P.h[0] = __floats2half2_rn(v[0], v[1]);
    P.h[1] = __floats2half2_rn(v[2], v[3]);
    P.h[2] = __floats2half2_rn(v[4], v[5]);
    P.h[3] = __floats2half2_rn(v[6], v[7]);
    g0[node * 8 + l] = P.u;
    if (write8) p0[node * 8 + l] = pack_fp8x8(v);
    if (do_pool) {
        const float4* s4 = (const float4*)s;
        float4 a = s4[2 * l], b = s4[2 * l + 1];
        float dot = f0.x * a.x + f0.y * a.y + f0.z * a.z + f0.w * a.w
                  + f1.x * b.x + f1.y * b.y + f1.z * b.z + f1.w * b.w;
        #pragma unroll
        for (int m = 1; m <= 4; m <<= 1) dot += __shfl_xor(dot, m, 64);
        float sig = 1.0f / (1.0f + expf(-dot));
        out[node * 16 + 2 * l]     = make_float4(sig * f0.x, sig * f0.y, sig * f0.z, sig * f0.w);
        out[node * 16 + 2 * l + 1] = make_float4(sig * f1.x, sig * f1.y, sig * f1.z, sig * f1.w);
    }
}

// ---- fp8 hop: gather 64B rows, f32 accumulate, write f16 (pool) + fp8 ---
// wave per node; lane = 8*g + l. Divergence-free shuffles (wave-uniform
// tiers on dcap); e-slots e = g + 8k, k in 0..7.

#define FP8_SLOT(K)                                                        \
    {                                                                      \
        int e0 = g + 8 * (K), e1 = e0 + 8;                                 \
        int u0 = __shfl(idx, e0, 64);                                      \
        int u1 = __shfl(idx, e1, 64);                                      \
        uint2 q0 = gin8[(size_t)u0 * 8 + l];                               \
        uint2 q1 = gin8[(size_t)u1 * 8 + l];                               \
        if (e0 < dcap) acc_fp8x8(q0, acc);                                 \
        if (e1 < dcap) acc_fp8x8(q1, acc);                                 \
    }

__global__ void spmm_hop_fp8(const uint2* __restrict__ gin8,
                             const int* __restrict__ offsets,
                             const int* __restrict__ csr,
                             const float* __restrict__ norm,
                             uint4* __restrict__ gout16,
                             uint2* __restrict__ gout8,
                             int n, int write8) {
    int lane = threadIdx.x & 63;
    int node = blockIdx.x * 4 + (threadIdx.x >> 6);
    if (node >= n) return;          // wave-uniform exit
    int g = lane >> 3;
    int l = lane & 7;
    int beg = offsets[node], end = offsets[node + 1];
    int deg = end - beg;
    int dcap = deg < 64 ? deg : 64;
    int idx = (lane < dcap) ? csr[beg + lane] : 0;

    float acc[8] = {0.f, 0.f, 0.f, 0.f, 0.f, 0.f, 0.f, 0.f};
    FP8_SLOT(0)                       // edges 0..15
    if (dcap > 16) FP8_SLOT(2)        // edges 16..31   (wave-uniform tier)
    if (dcap > 32) { FP8_SLOT(4) FP8_SLOT(6) }   // edges 32..63
    for (int i = beg + 64 + g; i < end; i += 8) {   // deg>64: essentially never
        acc_fp8x8(gin8[(size_t)csr[i] * 8 + l], acc);
    }

    // reduce across the 8 edge-subgroups (lane bits 3,4,5) in f32
    #pragma unroll
    for (int m = 8; m <= 32; m <<= 1) {
        #pragma unroll
        for (int jj = 0; jj < 8; ++jj) acc[jj] += __shfl_xor(acc[jj], m, 64);
    }

    if (g == 0) {
        float nv = norm[node];
        float gv[8];
        #pragma unroll
        for (int jj = 0; jj < 8; ++jj) gv[jj] = acc[jj] * nv * nv;  // g = h*nv
        U4H P;
        P.h[0] = __floats2half2_rn(gv[0], gv[1]);
        P.h[1] = __floats2half2_rn(gv[2], gv[3]);
        P.h[2] = __floats2half2_rn(gv[4], gv[5]);
        P.h[3] = __floats2half2_rn(gv[6], gv[7]);
        gout16[node * 8 + l] = P.u;
        if (write8) gout8[node * 8 + l] = pack_fp8x8(gv);
    }
}

// ---- f16 hop (fallback path, r10) ---------------------------------------

__global__ void spmm_hop(const uint4* __restrict__ gin, const int* __restrict__ offsets,
                         const int* __restrict__ csr, const float* __restrict__ norm,
                         const float* __restrict__ s, uint4* __restrict__ gout,
                         float4* __restrict__ out, int n, int do_pool, int write_g) {
    int lane = threadIdx.x & 63;
    int node = blockIdx.x * 4 + (threadIdx.x >> 6);
    if (node >= n) return;
    int g = lane >> 3;
    int l = lane & 7;
    int beg = offsets[node], end = offsets[node + 1];
    int deg = end - beg;
    int dcap = deg < 64 ? deg : 64;
    int idx = (lane < dcap) ? csr[beg + lane] : 0;

    __half2 z = __floats2half2_rn(0.f, 0.f);
    __half2 ah0 = z, ah1 = z, ah2 = z, ah3 = z;
    {
        int e0 = g, e1 = g + 8, e2 = g + 16, e3 = g + 24;
        int u0 = __shfl(idx, e0, 64);
        int u1 = __shfl(idx, e1, 64);
        int u2 = __shfl(idx, e2, 64);
        int u3 = __shfl(idx, e3, 64);
        U4H A, B, C, Dd;
        A.u = gin[(size_t)u0 * 8 + l];
        B.u = gin[(size_t)u1 * 8 + l];
        C.u = gin[(size_t)u2 * 8 + l];
        Dd.u = gin[(size_t)u3 * 8 + l];
        if (e0 < dcap) { ah0 = __hadd2(ah0, A.h[0]); ah1 = __hadd2(ah1, A.h[1]); ah2 = __hadd2(ah2, A.h[2]); ah3 = __hadd2(ah3, A.h[3]); }
        if (e1 < dcap) { ah0 = __hadd2(ah0, B.h[0]); ah1 = __hadd2(ah1, B.h[1]); ah2 = __hadd2(ah2, B.h[2]); ah3 = __hadd2(ah3, B.h[3]); }
        if (e2 < dcap) { ah0 = __hadd2(ah0, C.h[0]); ah1 = __hadd2(ah1, C.h[1]); ah2 = __hadd2(ah2, C.h[2]); ah3 = __hadd2(ah3, C.h[3]); }
        if (e3 < dcap) { ah0 = __hadd2(ah0, Dd.h[0]); ah1 = __hadd2(ah1, Dd.h[1]); ah2 = __hadd2(ah2, Dd.h[2]); ah3 = __hadd2(ah3, Dd.h[3]); }
    }
    if (dcap > 32) {
        int e0 = g + 32, e1 = g + 40, e2 = g + 48, e3 = g + 56;
        int u0 = __shfl(idx, e0, 64);
        int u1 = __shfl(idx, e1, 64);
        int u2 = __shfl(idx, e2, 64);
        int u3 = __shfl(idx, e3, 64);
        U4H A, B, C, Dd;
        A.u = gin[(size_t)u0 * 8 + l];
        B.u = gin[(size_t)u1 * 8 + l];
        C.u = gin[(size_t)u2 * 8 + l];
        Dd.u = gin[(size_t)u3 * 8 + l];
        if (e0 < dcap) { ah0 = __hadd2(ah0, A.h[0]); ah1 = __hadd2(ah1, A.h[1]); ah2 = __hadd2(ah2, A.h[2]); ah3 = __hadd2(ah3, A.h[3]); }
        if (e1 < dcap) { ah0 = __hadd2(ah0, B.h[0]); ah1 = __hadd2(ah1, B.h[1]); ah2 = __hadd2(ah2, B.h[2]); ah3 = __hadd2(ah3, B.h[3]); }
        if (e2 < dcap) { ah0 = __hadd2(ah0, C.h[0]); ah1 = __hadd2(ah1, C.h[1]); ah2 = __hadd2(ah2, C.h[2]); ah3 = __hadd2(ah3, C.h[3]); }
        if (e3 < dcap) { ah0 = __hadd2(ah0, Dd.h[0]); ah1 = __hadd2(ah1, Dd.h[1]); ah2 = __hadd2(ah2, Dd.h[2]); ah3 = __hadd2(ah3, Dd.h[3]); }
    }

    float2 q0 = __half22float2(ah0), q1 = __half22float2(ah1);
    float2 q2 = __half22float2(ah2), q3 = __half22float2(ah3);
    float acc[8] = {q0.x, q0.y, q1.x, q1.y, q2.x, q2.y, q3.x, q3.y};

    for (int i = beg + 64 + g; i < end; i += 8) {
        U4H P; P.u = gin[(size_t)csr[i] * 8 + l];
        float2 a0 = __half22float2(P.h[0]), a1 = __half22float2(P.h[1]);
        float2 a2 = __half22float2(P.h[2]), a3 = __half22float2(P.h[3]);
        acc[0] += a0.x; acc[1] += a0.y; acc[2] += a1.x; acc[3] += a1.y;
        acc[4] += a2.x; acc[5] += a2.y; acc[6] += a3.x; acc[7] += a3.y;
    }

    #pragma unroll
    for (int m = 8; m <= 32; m <<= 1) {
        #pragma unroll
        for (int jj = 0; jj < 8; ++jj) acc[jj] += __shfl_xor(acc[jj], m, 64);
    }

    float nv = norm[node];
    float h[8];
    #pragma unroll
    for (int jj = 0; jj < 8; ++jj) h[jj] = acc[jj] * nv;

    float sig = 0.f;
    if (do_pool) {
        const float4* s4 = (const float4*)s;
        float4 a = s4[2 * l], b = s4[2 * l + 1];
        float dot = h[0] * a.x + h[1] * a.y + h[2] * a.z + h[3] * a.w
                  + h[4] * b.x + h[5] * b.y + h[6] * b.z + h[7] * b.w;
        #pragma unroll
        for (int m = 1; m <= 4; m <<= 1) dot += __shfl_xor(dot, m, 64);
        sig = 1.0f / (1.0f + expf(-dot));
    }

    if (g == 0) {
        if (write_g) {
            U4H P;
            P.h[0] = __floats2half2_rn(h[0] * nv, h[1] * nv);
            P.h[1] = __floats2half2_rn(h[2] * nv, h[3] * nv);
            P.h[2] = __floats2half2_rn(h[4] * nv, h[5] * nv);
            P.h[3] = __floats2half2_rn(h[6] * nv, h[7] * nv);
            gout[node * 8 + l] = P.u;
        }
        if (do_pool) {
            float4 o0 = out[node * 16 + 2 * l];
            float4 o1 = out[node * 16 + 2 * l + 1];
            o0.x += sig * h[0]; o0.y += sig * h[1]; o0.z += sig * h[2]; o0.w += sig * h[3];
            o1.x += sig * h[4]; o1.y += sig * h[5]; o1.z += sig * h[6]; o1.w += sig * h[7];
            out[node * 16 + 2 * l]     = o0;
            out[node * 16 + 2 * l + 1] = o1;
        }
    }
}

// ---- deferred pooling epilogue (reads the 11 f16 buffers) ----------------

__global__ void pool_epilogue(const uint4* __restrict__ gbase, size_t gstride,
                              const float* __restrict__ norm,
                              const float* __restrict__ s,
                              float4* __restrict__ out, int N) {
    int t0 = blockIdx.x * blockDim.x + threadIdx.x;
    int node = t0 >> 3;
    int l = t0 & 7;
    if (node >= N) return;
    float inv_nv = 1.0f / norm[node];
    const float4* s4 = (const float4*)s;
    float4 sa = s4[2 * l], sb = s4[2 * l + 1];
    float o[8] = {0.f, 0.f, 0.f, 0.f, 0.f, 0.f, 0.f, 0.f};
    for (int t = 0; t <= KHOPS; ++t) {
        U4H P; P.u = gbase[(size_t)t * gstride + (size_t)node * 8 + l];
        float2 a0 = __half22float2(P.h[0]), a1 = __half22float2(P.h[1]);
        float2 a2 = __half22float2(P.h[2]), a3 = __half22float2(P.h[3]);
        float gf[8] = {a0.x, a0.y, a1.x, a1.y, a2.x, a2.y, a3.x, a3.y};
        float dot = gf[0] * sa.x + gf[1] * sa.y + gf[2] * sa.z + gf[3] * sa.w
                  + gf[4] * sb.x + gf[5] * sb.y + gf[6] * sb.z + gf[7] * sb.w;
        #pragma unroll
        for (int m = 1; m <= 4; m <<= 1) dot += __shfl_xor(dot, m, 64);
        float sig = 1.0f / (1.0f + expf(-dot * inv_nv));
        float sc = sig * inv_nv;
        #pragma unroll
        for (int j = 0; j < 8; ++j) o[j] += sc * gf[j];
    }
    out[node * 16 + 2 * l]     = make_float4(o[0], o[1], o[2], o[3]);
    out[node * 16 + 2 * l + 1] = make_float4(o[4], o[5], o[6], o[7]);
}

// ---- launcher -----------------------------------------------------------

extern "C" void kernel_launch(void* const* d_in, const int* in_sizes, int n_in,
                              void* d_out, int out_size, void* d_ws, size_t ws_size,
                              hipStream_t stream) {
    const float* feat = (const float*)d_in[0];
    const float* s    = (const float*)d_in[1];
    const int*   src  = (const int*)d_in[2];
    const int*   dst  = (const int*)d_in[3];

    int N = in_sizes[0] / D;
    int E = in_sizes[2];
    int NR   = (N + RB - 1) / RB;          // 98 ranges  (<= NRMAX)
    int NBLK = (E + EB - 1) / EB;          // 782 edge blocks
    int M    = NR * NBLK;
    int nchA = (M + 1023) / 1024;

    // fixed workspace layout
    int*   offsets  = (int*)d_ws;                  // N+1
    int*   csr      = offsets + (N + 1);           // E
    float* norm     = (float*)(csr + E);           // N
    int*   countsA  = (int*)(norm + N);            // M
    int*   baseA    = countsA + M;                 // M
    int*   bsumA    = baseA + M;                   // nchA
    uintptr_t p = (uintptr_t)(bsumA + nchA);
    p = (p + 255) & ~(uintptr_t)255;
    uint4* gbase = (uint4*)p;                      // f16 rows: N*8 uint4 per buffer
    size_t gstride = (size_t)N * 8;                // uint4 per f16 buffer (12.8 MB)
    uint2* pbase = (uint2*)(gbase + (size_t)(KHOPS + 1) * gstride);  // fp8 ping-pong
    size_t pstride = (size_t)N * 8;                // uint2 per fp8 buffer (6.4 MB)

    size_t fixed_bytes = (uintptr_t)gbase - (uintptr_t)d_ws;
    size_t need_f16 = (size_t)(KHOPS + 1) * gstride * sizeof(uint4);
    size_t need_fp8 = 2 * pstride * sizeof(uint2);
    int mode;   // 2 = fp8 gathers + deferred pool, 1 = f16 deferred, 0 = f16 fused
    if (ws_size >= fixed_bytes + need_f16 + need_fp8) mode = 2;
    else if (ws_size >= fixed_bytes + need_f16)       mode = 1;
    else                                              mode = 0;

    // ebuf2 (E u32 = 6.4MB) aliases f16 buffer #1 (first written after
    // range_build has consumed ebuf2)
    unsigned int* ebuf2 = (unsigned int*)(gbase + gstride);

    // multisplit CSR build (zero global atomics)
    countA<<<NBLK, 256, 0, stream>>>(dst, countsA, E, NR, NBLK);
    block_sums<<<nchA, 256, 0, stream>>>(countsA, bsumA, M);
    scan_bsums<<<1, 1024, 0, stream>>>(bsumA, nchA);
    gen_scan2<<<nchA, 1024, 0, stream>>>(countsA, bsumA, baseA, M);
    passA2<<<NBLK, 256, 0, stream>>>(src, dst, baseA, ebuf2, E, NR, NBLK);
    range_build<<<NR, RB, 0, stream>>>(ebuf2, baseA, offsets, norm, csr, N, E, NR, NBLK);

    float4* outp = (float4*)d_out;
    int nb_node8 = (N * 8 + 255) / 256;
    int nb_spmm  = (N + 3) / 4;

    if (mode == 2) {
        hop0<<<nb_node8, 256, 0, stream>>>((const float4*)feat, s, norm, gbase,
                                           pbase, outp, N, 0, 1);
        for (int t = 0; t < KHOPS; ++t) {
            spmm_hop_fp8<<<nb_spmm, 256, 0, stream>>>(
                pbase + (size_t)(t & 1) * pstride, offsets, csr, norm,
                gbase + (size_t)(t + 1) * gstride,
                pbase + (size_t)((t + 1) & 1) * pstride,
                N, (t < KHOPS - 1) ? 1 : 0);
        }
        pool_epilogue<<<nb_node8, 256, 0, stream>>>(gbase, gstride, norm, s, outp, N);
    } else if (mode == 1) {
        hop0<<<nb_node8, 256, 0, stream>>>((const float4*)feat, s, norm, gbase,
                                           (uint2*)nullptr, outp, N, 0, 0);
        for (int t = 0; t < KHOPS; ++t) {
            spmm_hop<<<nb_spmm, 256, 0, stream>>>(
                gbase + (size_t)t * gstride, offsets, csr, norm, s,
                gbase + (size_t)(t + 1) * gstride, outp, N, 0, 1);
        }
        pool_epilogue<<<nb_node8, 256, 0, stream>>>(gbase, gstride, norm, s, outp, N);
    } else {
        hop0<<<nb_node8, 256, 0, stream>>>((const float4*)feat, s, norm, gbase,
                                           (uint2*)nullptr, outp, N, 1, 0);
        uint4* gin = gbase;
        uint4* gout = gbase + gstride;
        for (int t = 0; t < KHOPS; ++t) {
            spmm_hop<<<nb_spmm, 256, 0, stream>>>(
                gin, offsets, csr, norm, s, gout, outp, N, 1, (t < KHOPS - 1) ? 1 : 0);
            uint4* tmp = gin; gin = gout; gout = tmp;
        }
    }
}